// Round 6
// baseline (240.766 us; speedup 1.0000x reference)
//
#include <hip/hip_runtime.h>

// Problem constants (match reference)
#define H_    64
#define W_    1024
#define NPT   65536            // H*W
#define NTOT  131072           // B*NPT
#define C1_   64
#define C2_   128
#define CIN_  192
#define CM_   128
#define NS_   3
#define DIST2_ 10000.0f
#define BN_EPS_ 1e-5f
#define NSLOT 32               // BN-stat accumulator slots

typedef __attribute__((ext_vector_type(8))) short short8;   // 8 bf16
typedef __attribute__((ext_vector_type(4))) float floatx4;  // MFMA C/D

static __device__ __forceinline__ unsigned short f2bf(float f) {
    unsigned int u = __float_as_uint(f);
    u += 0x7fffu + ((u >> 16) & 1u);      // round-nearest-even
    return (unsigned short)(u >> 16);
}
static __device__ __forceinline__ float bflo(unsigned u) { return __uint_as_float(u << 16); }
static __device__ __forceinline__ float bfhi(unsigned u) { return __uint_as_float(u & 0xffff0000u); }
static __device__ __forceinline__ unsigned packbf(float a, float b) {
    return (unsigned)f2bf(a) | ((unsigned)f2bf(b) << 16);
}

// ---------------------------------------------------------------------------
// K0: blocks 0..19 build fragment-major bf16 weights
// (w0F[((kk*8+nt)*64+lane)*8+j] -> coalesced 1KB B-frag wave loads);
// blocks 20.. do structured-grid KNN (reference 5x5 row-major scan order).
// ---------------------------------------------------------------------------
__global__ __launch_bounds__(256) void prep_knn_kernel(
    const float* __restrict__ w0, const float* __restrict__ w1,
    const float* __restrict__ xyz1, const float* __restrict__ xyz2,
    unsigned short* __restrict__ w0F, unsigned short* __restrict__ w1F,
    int* __restrict__ sel, float* __restrict__ wgt)
{
    const int blk = blockIdx.x;
    if (blk < 20) {
        int tid = blk * 256 + threadIdx.x;
        if (tid < 3072) {                       // w0F: 6kk x 8nt x 64lane chunks
            int c = tid, lane = c & 63, nt = (c >> 6) & 7, kk = c >> 9;
            int n = nt * 16 + (lane & 15);
            int kb = kk * 32 + (lane >> 4) * 8;
            #pragma unroll
            for (int j = 0; j < 8; j++)
                w0F[(size_t)c * 8 + j] = f2bf(w0[(size_t)(kb + j) * CM_ + n]);
        } else if (tid < 5120) {                // w1F: 4kk x 8nt x 64lane
            int c = tid - 3072, lane = c & 63, nt = (c >> 6) & 7, kk = c >> 9;
            int n = nt * 16 + (lane & 15);
            int kb = kk * 32 + (lane >> 4) * 8;
            #pragma unroll
            for (int j = 0; j < 8; j++)
                w1F[(size_t)c * 8 + j] = f2bf(w1[(size_t)(kb + j) * CM_ + n]);
        }
        return;
    }

    int pt = (blk - 20) * 256 + threadIdx.x;
    if (pt >= NTOT) return;
    int bidx = pt / NPT, n = pt % NPT;
    int h = n / W_, w = n % W_;

    const float* p1 = xyz1 + (size_t)pt * 3;
    float x1 = p1[0], y1 = p1[1], z1 = p1[2];
    const float* x2b = xyz2 + (size_t)bidx * NPT * 3;

    int   s0 = 0, s1 = 0, s2 = 0;
    float d0 = 0.f, d1 = 0.f, d2 = 0.f;
    int cnt = 0;
    for (int dh = -2; dh <= 2; dh++) {
        int nh = h + dh;
        bool okh = (nh >= 0) && (nh < H_);
        for (int dw = -2; dw <= 2; dw++) {
            int nw = w + dw;
            if (!(okh && nw >= 0 && nw < W_)) continue;
            int nidx = nh * W_ + nw;
            const float* p2 = x2b + (size_t)nidx * 3;
            float dx = p2[0] - x1, dy = p2[1] - y1, dz = p2[2] - z1;
            float sq = dx * dx + dy * dy + dz * dz;
            if (sq < DIST2_ && cnt < NS_) {
                if (cnt == 0)      { s0 = nidx; d0 = sq; }
                else if (cnt == 1) { s1 = nidx; d1 = sq; }
                else               { s2 = nidx; d2 = sq; }
                cnt++;
            }
        }
    }
    float self2 = x1 * x1 + y1 * y1 + z1 * z1;
    float dd0 = (cnt > 0) ? d0 : self2;
    float dd1 = (cnt > 1) ? d1 : self2;
    float dd2 = (cnt > 2) ? d2 : self2;
    dd0 = fmaxf(dd0, 1e-10f); dd1 = fmaxf(dd1, 1e-10f); dd2 = fmaxf(dd2, 1e-10f);
    float i0 = 1.0f / dd0, i1 = 1.0f / dd1, i2 = 1.0f / dd2;
    float norm = i0 + i1 + i2;
    sel[(size_t)pt * NS_ + 0] = (cnt > 0) ? s0 : 0;
    sel[(size_t)pt * NS_ + 1] = (cnt > 1) ? s1 : 0;
    sel[(size_t)pt * NS_ + 2] = (cnt > 2) ? s2 : 0;
    wgt[(size_t)pt * NS_ + 0] = (cnt > 0) ? i0 / norm : 0.f;
    wgt[(size_t)pt * NS_ + 1] = (cnt > 1) ? i1 / norm : 0.f;
    wgt[(size_t)pt * NS_ + 2] = (cnt > 2) ? i2 / norm : 0.f;
}

// ---------------------------------------------------------------------------
// bnfin: 1-block kernel. Reduce NSLOT slot-accumulators -> per-channel BN
// scale/shift into bnp[0:128]=scale, bnp[128:256]=shift.
// ---------------------------------------------------------------------------
__global__ __launch_bounds__(128) void bnfin_kernel(
    const float* __restrict__ slots, const float* __restrict__ g,
    const float* __restrict__ be, float* __restrict__ bnp)
{
    int t = threadIdx.x;                // 128 threads, one channel each
    float s = 0.f, q2 = 0.f;
    #pragma unroll
    for (int sl = 0; sl < NSLOT; sl++) {
        s  += slots[sl * 256 + t];
        q2 += slots[sl * 256 + CM_ + t];
    }
    const float invn = 1.0f / (float)NTOT;
    float mu = s * invn, var = q2 * invn - mu * mu;
    float sc = g[t] * rsqrtf(var + BN_EPS_);
    bnp[t] = sc;
    bnp[CM_ + t] = be[t] - mu * sc;
}

// ---------------------------------------------------------------------------
// K1: LDS-free A-fragment construction. Each lane (m,q) of wave wv owns row
// pbase+wv*16+m and k-chunk q*8 (+kk*32): feat1 chunks read directly from
// global; interp chunks computed in-register from 3 gathered neighbor rows.
// No staging barriers. MFMA with frag-major w0F; y0 stored frag-packed bf16;
// BN0 stats on rounded values -> slotted atomics.
// ---------------------------------------------------------------------------
__global__ __launch_bounds__(256, 4) void fused1_kernel(
    const float* __restrict__ feat1, const float* __restrict__ feat2,
    const int* __restrict__ sel, const float* __restrict__ wgt,
    const unsigned short* __restrict__ w0F, const float* __restrict__ b0,
    uint2* __restrict__ y0w, float* __restrict__ slots0)
{
    __shared__ float wsum[4][CM_], wsq[4][CM_];

    const int t = threadIdx.x;
    const int blk = blockIdx.x;
    const int pbase = blk * 64;
    const int bidx = blk >> 10;                 // 1024 blocks per batch
    const int wv = t >> 6, lane = t & 63;
    const int m = lane & 15, q = lane >> 4;
    const int row = pbase + wv * 16 + m;        // this lane's point

    // neighbor indices + weights (4x redundant across q; L1 broadcast)
    int   s0 = sel[(size_t)row * NS_ + 0];
    int   s1 = sel[(size_t)row * NS_ + 1];
    int   s2 = sel[(size_t)row * NS_ + 2];
    float g0v = wgt[(size_t)row * NS_ + 0];
    float g1v = wgt[(size_t)row * NS_ + 1];
    float g2v = wgt[(size_t)row * NS_ + 2];
    const float* f2b = feat2 + (size_t)bidx * NPT * C2_;
    const float* r0 = f2b + (size_t)s0 * C2_;
    const float* r1 = f2b + (size_t)s1 * C2_;
    const float* r2 = f2b + (size_t)s2 * C2_;

    short8 afrag[6];
    // feat1 -> kk=0,1 (k = kk*32 + q*8 + j, j<8; k<64)
    #pragma unroll
    for (int kk = 0; kk < 2; kk++) {
        const float* src = feat1 + (size_t)row * C1_ + kk * 32 + q * 8;
        float4 fa = *(const float4*)(src);
        float4 fb = *(const float4*)(src + 4);
        short8 a;
        a[0] = f2bf(fa.x); a[1] = f2bf(fa.y); a[2] = f2bf(fa.z); a[3] = f2bf(fa.w);
        a[4] = f2bf(fb.x); a[5] = f2bf(fb.y); a[6] = f2bf(fb.z); a[7] = f2bf(fb.w);
        afrag[kk] = a;
    }
    // IDW interp -> kk=2..5 (interp channel ci = (kk-2)*32 + q*8 + j)
    #pragma unroll
    for (int kc = 0; kc < 4; kc++) {
        int ci = kc * 32 + q * 8;
        float4 a0 = *(const float4*)(r0 + ci), a1 = *(const float4*)(r0 + ci + 4);
        float4 c0 = *(const float4*)(r1 + ci), c1 = *(const float4*)(r1 + ci + 4);
        float4 e0 = *(const float4*)(r2 + ci), e1 = *(const float4*)(r2 + ci + 4);
        short8 a;
        a[0] = f2bf(g0v * a0.x + g1v * c0.x + g2v * e0.x);
        a[1] = f2bf(g0v * a0.y + g1v * c0.y + g2v * e0.y);
        a[2] = f2bf(g0v * a0.z + g1v * c0.z + g2v * e0.z);
        a[3] = f2bf(g0v * a0.w + g1v * c0.w + g2v * e0.w);
        a[4] = f2bf(g0v * a1.x + g1v * c1.x + g2v * e1.x);
        a[5] = f2bf(g0v * a1.y + g1v * c1.y + g2v * e1.y);
        a[6] = f2bf(g0v * a1.z + g1v * c1.z + g2v * e1.z);
        a[7] = f2bf(g0v * a1.w + g1v * c1.w + g2v * e1.w);
        afrag[2 + kc] = a;
    }

    floatx4 acc[8];
    #pragma unroll
    for (int nt = 0; nt < 8; nt++) acc[nt] = (floatx4){0.f, 0.f, 0.f, 0.f};

    #pragma unroll
    for (int kk = 0; kk < 6; kk++) {
        #pragma unroll
        for (int nt = 0; nt < 8; nt++) {
            short8 bw = *(const short8*)(w0F + ((size_t)(kk * 8 + nt) * 64 + lane) * 8);
            acc[nt] = __builtin_amdgcn_mfma_f32_16x16x32_bf16(afrag[kk], bw, acc[nt], 0, 0, 0);
        }
    }

    // epilogue: round to bf16, store frag-packed, stats on rounded values
    #pragma unroll
    for (int nt = 0; nt < 8; nt++) {
        int n = nt * 16 + m;
        float bv = b0[n];
        unsigned u0 = packbf(acc[nt][0] + bv, acc[nt][1] + bv);
        unsigned u1 = packbf(acc[nt][2] + bv, acc[nt][3] + bv);
        y0w[((size_t)(blk * 4 + wv) * 8 + nt) * 64 + lane] = make_uint2(u0, u1);
        float v0 = bflo(u0), v1 = bfhi(u0), v2 = bflo(u1), v3 = bfhi(u1);
        float s  = v0 + v1 + v2 + v3;
        float q2 = v0 * v0 + v1 * v1 + v2 * v2 + v3 * v3;
        s += __shfl_xor(s, 16, 64); q2 += __shfl_xor(q2, 16, 64);
        s += __shfl_xor(s, 32, 64); q2 += __shfl_xor(q2, 32, 64);
        if (q == 0) { wsum[wv][n] = s; wsq[wv][n] = q2; }
    }
    __syncthreads();

    float* slot = slots0 + (size_t)(blk & (NSLOT - 1)) * 256;
    if (t < CM_)
        atomicAdd(&slot[t], wsum[0][t] + wsum[1][t] + wsum[2][t] + wsum[3][t]);
    else
        atomicAdd(&slot[t], wsq[0][t - CM_] + wsq[1][t - CM_] + wsq[2][t - CM_] + wsq[3][t - CM_]);
}

// ---------------------------------------------------------------------------
// K2: load y0 frags (coalesced), BN0+ReLU (scale/shift from bnp0, no
// reduction), D->A transform via LDS; MFMA matmul1 with w1F; y1 frag-packed
// bf16 + BN1 stats.
// ---------------------------------------------------------------------------
__global__ __launch_bounds__(256) void fused2_kernel(
    const uint2* __restrict__ y0w, const float* __restrict__ bnp0,
    const unsigned short* __restrict__ w1F, const float* __restrict__ b1,
    uint2* __restrict__ y1w, float* __restrict__ slots1)
{
    __shared__ unsigned short x1s[64][CM_ + 8];   // pitch 136 shorts
    __shared__ float wsum[4][CM_], wsq[4][CM_];

    const int t = threadIdx.x;
    const int blk = blockIdx.x;
    const int wv = t >> 6, lane = t & 63;
    const int m = lane & 15, q = lane >> 4;

    // y0 frags -> BN0+ReLU -> bf16 A-tile in LDS
    #pragma unroll
    for (int nt = 0; nt < 8; nt++) {
        int n = nt * 16 + m;
        float sc = bnp0[n], sh = bnp0[CM_ + n];
        uint2 u = y0w[((size_t)(blk * 4 + wv) * 8 + nt) * 64 + lane];
        float v0 = fmaxf(bflo(u.x) * sc + sh, 0.f);
        float v1 = fmaxf(bfhi(u.x) * sc + sh, 0.f);
        float v2 = fmaxf(bflo(u.y) * sc + sh, 0.f);
        float v3 = fmaxf(bfhi(u.y) * sc + sh, 0.f);
        int rb = wv * 16 + q * 4;
        x1s[rb + 0][n] = f2bf(v0);
        x1s[rb + 1][n] = f2bf(v1);
        x1s[rb + 2][n] = f2bf(v2);
        x1s[rb + 3][n] = f2bf(v3);
    }
    __syncthreads();

    const unsigned short* arow = &x1s[wv * 16 + m][q * 8];
    floatx4 acc[8];
    #pragma unroll
    for (int nt = 0; nt < 8; nt++) acc[nt] = (floatx4){0.f, 0.f, 0.f, 0.f};

    #pragma unroll
    for (int kk = 0; kk < 4; kk++) {
        short8 a = *(const short8*)(arow + kk * 32);
        #pragma unroll
        for (int nt = 0; nt < 8; nt++) {
            short8 bw = *(const short8*)(w1F + ((size_t)(kk * 8 + nt) * 64 + lane) * 8);
            acc[nt] = __builtin_amdgcn_mfma_f32_16x16x32_bf16(a, bw, acc[nt], 0, 0, 0);
        }
    }

    #pragma unroll
    for (int nt = 0; nt < 8; nt++) {
        int n = nt * 16 + m;
        float bv = b1[n];
        unsigned u0 = packbf(acc[nt][0] + bv, acc[nt][1] + bv);
        unsigned u1 = packbf(acc[nt][2] + bv, acc[nt][3] + bv);
        y1w[((size_t)(blk * 4 + wv) * 8 + nt) * 64 + lane] = make_uint2(u0, u1);
        float v0 = bflo(u0), v1 = bfhi(u0), v2 = bflo(u1), v3 = bfhi(u1);
        float s  = v0 + v1 + v2 + v3;
        float q2 = v0 * v0 + v1 * v1 + v2 * v2 + v3 * v3;
        s += __shfl_xor(s, 16, 64); q2 += __shfl_xor(q2, 16, 64);
        s += __shfl_xor(s, 32, 64); q2 += __shfl_xor(q2, 32, 64);
        if (q == 0) { wsum[wv][n] = s; wsq[wv][n] = q2; }
    }
    __syncthreads();

    float* slot = slots1 + (size_t)(blk & (NSLOT - 1)) * 256;
    if (t < CM_)
        atomicAdd(&slot[t], wsum[0][t] + wsum[1][t] + wsum[2][t] + wsum[3][t]);
    else
        atomicAdd(&slot[t], wsq[0][t - CM_] + wsq[1][t - CM_] + wsq[2][t - CM_] + wsq[3][t - CM_]);
}

// ---------------------------------------------------------------------------
// K3: barrier-free BN1+ReLU on y1 frags (scale/shift from bnp1) -> f32 out.
// ---------------------------------------------------------------------------
__global__ __launch_bounds__(256) void bn_out_kernel(
    const uint2* __restrict__ y1w, const float* __restrict__ bnp1,
    float* __restrict__ out)
{
    const int t = threadIdx.x;
    const int blk = blockIdx.x;
    const int wv = t >> 6, lane = t & 63;
    const int m = lane & 15, q = lane >> 4;

    #pragma unroll
    for (int nt = 0; nt < 8; nt++) {
        int n = nt * 16 + m;
        float sc = bnp1[n], sh = bnp1[CM_ + n];
        uint2 u = y1w[((size_t)(blk * 4 + wv) * 8 + nt) * 64 + lane];
        int rb = blk * 64 + wv * 16 + q * 4;
        out[(size_t)(rb + 0) * CM_ + n] = fmaxf(bflo(u.x) * sc + sh, 0.f);
        out[(size_t)(rb + 1) * CM_ + n] = fmaxf(bfhi(u.x) * sc + sh, 0.f);
        out[(size_t)(rb + 2) * CM_ + n] = fmaxf(bflo(u.y) * sc + sh, 0.f);
        out[(size_t)(rb + 3) * CM_ + n] = fmaxf(bfhi(u.y) * sc + sh, 0.f);
    }
}

// ---------------------------------------------------------------------------
extern "C" void kernel_launch(void* const* d_in, const int* in_sizes, int n_in,
                              void* d_out, int out_size, void* d_ws, size_t ws_size,
                              hipStream_t stream)
{
    const float* xyz1  = (const float*)d_in[0];
    const float* xyz2  = (const float*)d_in[1];
    const float* feat1 = (const float*)d_in[2];
    const float* feat2 = (const float*)d_in[3];
    const float* w0    = (const float*)d_in[4];
    const float* b0    = (const float*)d_in[5];
    const float* g0    = (const float*)d_in[6];
    const float* be0   = (const float*)d_in[7];
    const float* w1    = (const float*)d_in[8];
    const float* b1    = (const float*)d_in[9];
    const float* g1    = (const float*)d_in[10];
    const float* be1   = (const float*)d_in[11];
    float* out = (float*)d_out;

    char* ws = (char*)d_ws;
    // ws: slots0 32K | slots1 32K | bnp0 1K | bnp1 1K | sel 1.5M | wgt 1.5M
    //     | w0F 48K | w1F 32K | y0w 33.5M | y1w 33.5M
    float* slots0       = (float*)(ws);
    float* slots1       = (float*)(ws + (size_t)NSLOT * 256 * 4);
    float* bnp0         = (float*)(ws + 2 * (size_t)NSLOT * 256 * 4);
    float* bnp1         = bnp0 + 256;
    char*  p            = (char*)(bnp1 + 256);
    int*   sel          = (int*)p;             p += (size_t)NTOT * NS_ * 4;
    float* wgt          = (float*)p;           p += (size_t)NTOT * NS_ * 4;
    unsigned short* w0F = (unsigned short*)p;  p += (size_t)CIN_ * CM_ * 2;
    unsigned short* w1F = (unsigned short*)p;  p += (size_t)CM_ * CM_ * 2;
    uint2* y0w          = (uint2*)p;           p += (size_t)NTOT * CM_ * 2;
    uint2* y1w          = (uint2*)p;

    hipMemsetAsync(ws, 0, 2 * (size_t)NSLOT * 256 * 4, stream);  // zero stat slots

    prep_knn_kernel<<<20 + NTOT / 256, 256, 0, stream>>>(w0, w1, xyz1, xyz2,
                                                         w0F, w1F, sel, wgt);
    fused1_kernel<<<NTOT / 64, 256, 0, stream>>>(feat1, feat2, sel, wgt,
                                                 w0F, b0, y0w, slots0);
    bnfin_kernel<<<1, 128, 0, stream>>>(slots0, g0, be0, bnp0);
    fused2_kernel<<<NTOT / 64, 256, 0, stream>>>(y0w, bnp0, w1F, b1, y1w, slots1);
    bnfin_kernel<<<1, 128, 0, stream>>>(slots1, g1, be1, bnp1);
    bn_out_kernel<<<NTOT / 64, 256, 0, stream>>>(y1w, bnp1, out);
}

// Round 7
// 230.010 us; speedup vs baseline: 1.0468x; 1.0468x over previous
//
#include <hip/hip_runtime.h>

// Problem constants (match reference)
#define H_    64
#define W_    1024
#define NPT   65536            // H*W
#define NTOT  131072           // B*NPT
#define C1_   64
#define C2_   128
#define CIN_  192
#define CM_   128
#define NS_   3
#define DIST2_ 10000.0f
#define BN_EPS_ 1e-5f
#define NSLOT 32               // BN-stat accumulator slots

typedef __attribute__((ext_vector_type(8))) short short8;   // 8 bf16
typedef __attribute__((ext_vector_type(4))) float floatx4;  // MFMA C/D

static __device__ __forceinline__ unsigned short f2bf(float f) {
    unsigned int u = __float_as_uint(f);
    u += 0x7fffu + ((u >> 16) & 1u);      // round-nearest-even
    return (unsigned short)(u >> 16);
}
static __device__ __forceinline__ float bflo(unsigned u) { return __uint_as_float(u << 16); }
static __device__ __forceinline__ float bfhi(unsigned u) { return __uint_as_float(u & 0xffff0000u); }
static __device__ __forceinline__ unsigned packbf(float a, float b) {
    return (unsigned)f2bf(a) | ((unsigned)f2bf(b) << 16);
}

// ---------------------------------------------------------------------------
// K0: blocks 0..19 build fragment-major bf16 weights
// (w0F[((kk*8+nt)*64+lane)*8+j] -> coalesced 1KB B-frag wave loads);
// blocks 20.. do structured-grid KNN (reference 5x5 row-major scan order).
// ---------------------------------------------------------------------------
__global__ __launch_bounds__(256) void prep_knn_kernel(
    const float* __restrict__ w0, const float* __restrict__ w1,
    const float* __restrict__ xyz1, const float* __restrict__ xyz2,
    unsigned short* __restrict__ w0F, unsigned short* __restrict__ w1F,
    int* __restrict__ sel, float* __restrict__ wgt)
{
    const int blk = blockIdx.x;
    if (blk < 20) {
        int tid = blk * 256 + threadIdx.x;
        if (tid < 3072) {                       // w0F: 6kk x 8nt x 64lane chunks
            int c = tid, lane = c & 63, nt = (c >> 6) & 7, kk = c >> 9;
            int n = nt * 16 + (lane & 15);
            int kb = kk * 32 + (lane >> 4) * 8;
            #pragma unroll
            for (int j = 0; j < 8; j++)
                w0F[(size_t)c * 8 + j] = f2bf(w0[(size_t)(kb + j) * CM_ + n]);
        } else if (tid < 5120) {                // w1F: 4kk x 8nt x 64lane
            int c = tid - 3072, lane = c & 63, nt = (c >> 6) & 7, kk = c >> 9;
            int n = nt * 16 + (lane & 15);
            int kb = kk * 32 + (lane >> 4) * 8;
            #pragma unroll
            for (int j = 0; j < 8; j++)
                w1F[(size_t)c * 8 + j] = f2bf(w1[(size_t)(kb + j) * CM_ + n]);
        }
        return;
    }

    int pt = (blk - 20) * 256 + threadIdx.x;
    if (pt >= NTOT) return;
    int bidx = pt / NPT, n = pt % NPT;
    int h = n / W_, w = n % W_;

    const float* p1 = xyz1 + (size_t)pt * 3;
    float x1 = p1[0], y1 = p1[1], z1 = p1[2];
    const float* x2b = xyz2 + (size_t)bidx * NPT * 3;

    int   s0 = 0, s1 = 0, s2 = 0;
    float d0 = 0.f, d1 = 0.f, d2 = 0.f;
    int cnt = 0;
    for (int dh = -2; dh <= 2; dh++) {
        int nh = h + dh;
        bool okh = (nh >= 0) && (nh < H_);
        for (int dw = -2; dw <= 2; dw++) {
            int nw = w + dw;
            if (!(okh && nw >= 0 && nw < W_)) continue;
            int nidx = nh * W_ + nw;
            const float* p2 = x2b + (size_t)nidx * 3;
            float dx = p2[0] - x1, dy = p2[1] - y1, dz = p2[2] - z1;
            float sq = dx * dx + dy * dy + dz * dz;
            if (sq < DIST2_ && cnt < NS_) {
                if (cnt == 0)      { s0 = nidx; d0 = sq; }
                else if (cnt == 1) { s1 = nidx; d1 = sq; }
                else               { s2 = nidx; d2 = sq; }
                cnt++;
            }
        }
    }
    float self2 = x1 * x1 + y1 * y1 + z1 * z1;
    float dd0 = (cnt > 0) ? d0 : self2;
    float dd1 = (cnt > 1) ? d1 : self2;
    float dd2 = (cnt > 2) ? d2 : self2;
    dd0 = fmaxf(dd0, 1e-10f); dd1 = fmaxf(dd1, 1e-10f); dd2 = fmaxf(dd2, 1e-10f);
    float i0 = 1.0f / dd0, i1 = 1.0f / dd1, i2 = 1.0f / dd2;
    float norm = i0 + i1 + i2;
    sel[(size_t)pt * NS_ + 0] = (cnt > 0) ? s0 : 0;
    sel[(size_t)pt * NS_ + 1] = (cnt > 1) ? s1 : 0;
    sel[(size_t)pt * NS_ + 2] = (cnt > 2) ? s2 : 0;
    wgt[(size_t)pt * NS_ + 0] = (cnt > 0) ? i0 / norm : 0.f;
    wgt[(size_t)pt * NS_ + 1] = (cnt > 1) ? i1 / norm : 0.f;
    wgt[(size_t)pt * NS_ + 2] = (cnt > 2) ? i2 / norm : 0.f;
}

// ---------------------------------------------------------------------------
// bnfin: 1-block kernel. Reduce NSLOT slot-accumulators -> per-channel BN
// scale/shift into bnp[0:128]=scale, bnp[128:256]=shift.
// ---------------------------------------------------------------------------
__global__ __launch_bounds__(128) void bnfin_kernel(
    const float* __restrict__ slots, const float* __restrict__ g,
    const float* __restrict__ be, float* __restrict__ bnp)
{
    int t = threadIdx.x;                // 128 threads, one channel each
    float s = 0.f, q2 = 0.f;
    #pragma unroll
    for (int sl = 0; sl < NSLOT; sl++) {
        s  += slots[sl * 256 + t];
        q2 += slots[sl * 256 + CM_ + t];
    }
    const float invn = 1.0f / (float)NTOT;
    float mu = s * invn, var = q2 * invn - mu * mu;
    float sc = g[t] * rsqrtf(var + BN_EPS_);
    bnp[t] = sc;
    bnp[CM_ + t] = be[t] - mu * sc;
}

// ---------------------------------------------------------------------------
// K1: interp gather staged via LDS with channel-major coalesced mapping
// (32 consecutive lanes -> 32 consecutive float4 of one row); feat1 rows
// (contiguous) load DIRECTLY into A-frags, bypassing LDS. MFMA with
// frag-major w0F; y0 frag-packed bf16; BN0 stats on rounded values.
// ---------------------------------------------------------------------------
__global__ __launch_bounds__(256) void fused1_kernel(
    const float* __restrict__ feat1, const float* __restrict__ feat2,
    const int* __restrict__ sel, const float* __restrict__ wgt,
    const unsigned short* __restrict__ w0F, const float* __restrict__ b0,
    uint2* __restrict__ y0w, float* __restrict__ slots0)
{
    __shared__ unsigned short xstage[64][CM_ + 8];   // interp channels, pitch 136
    __shared__ int   selL[64][NS_];
    __shared__ float wgtL[64][NS_];
    __shared__ float wsum[4][CM_], wsq[4][CM_];

    const int t = threadIdx.x;
    const int blk = blockIdx.x;
    const int pbase = blk * 64;
    const int bidx = blk >> 10;                 // 1024 blocks per batch
    const int wv = t >> 6, lane = t & 63;
    const int m = lane & 15, q = lane >> 4;
    const int row = pbase + wv * 16 + m;        // this lane's point

    if (t < 64 * NS_) {
        ((int*)selL)[t]   = sel[(size_t)pbase * NS_ + t];
        ((float*)wgtL)[t] = wgt[(size_t)pbase * NS_ + t];
    }

    // feat1 -> afrag[0..1] directly from global (k = kk*32 + q*8 + j)
    short8 afrag[6];
    #pragma unroll
    for (int kk = 0; kk < 2; kk++) {
        const float* src = feat1 + (size_t)row * C1_ + kk * 32 + q * 8;
        float4 fa = *(const float4*)(src);
        float4 fb = *(const float4*)(src + 4);
        short8 a;
        a[0] = f2bf(fa.x); a[1] = f2bf(fa.y); a[2] = f2bf(fa.z); a[3] = f2bf(fa.w);
        a[4] = f2bf(fb.x); a[5] = f2bf(fb.y); a[6] = f2bf(fb.z); a[7] = f2bf(fb.w);
        afrag[kk] = a;
    }
    __syncthreads();

    // IDW interp -> xstage[:, 0:128]  (coalesced: 32 lanes span one row)
    const float* f2b = feat2 + (size_t)bidx * NPT * C2_;
    #pragma unroll
    for (int i = 0; i < 8; i++) {
        int idx = t + i * 256;
        int p = idx >> 5, c4 = (idx & 31) << 2;
        float ax = 0.f, ay = 0.f, az = 0.f, aw = 0.f;
        #pragma unroll
        for (int j = 0; j < NS_; j++) {
            float wj = wgtL[p][j];
            const float4 f = *(const float4*)(f2b + (size_t)selL[p][j] * C2_ + c4);
            ax += wj * f.x; ay += wj * f.y; az += wj * f.z; aw += wj * f.w;
        }
        ushort4 u;
        u.x = f2bf(ax); u.y = f2bf(ay); u.z = f2bf(az); u.w = f2bf(aw);
        *(ushort4*)&xstage[p][c4] = u;
    }
    __syncthreads();

    // interp A-frags from LDS (k-chunks 2..5 -> interp channels kc*32+q*8)
    #pragma unroll
    for (int kc = 0; kc < 4; kc++)
        afrag[2 + kc] = *(const short8*)&xstage[wv * 16 + m][kc * 32 + q * 8];

    floatx4 acc[8];
    #pragma unroll
    for (int nt = 0; nt < 8; nt++) acc[nt] = (floatx4){0.f, 0.f, 0.f, 0.f};

    #pragma unroll
    for (int kk = 0; kk < 6; kk++) {
        #pragma unroll
        for (int nt = 0; nt < 8; nt++) {
            short8 bw = *(const short8*)(w0F + ((size_t)(kk * 8 + nt) * 64 + lane) * 8);
            acc[nt] = __builtin_amdgcn_mfma_f32_16x16x32_bf16(afrag[kk], bw, acc[nt], 0, 0, 0);
        }
    }

    // epilogue: round to bf16, store frag-packed, stats on rounded values
    #pragma unroll
    for (int nt = 0; nt < 8; nt++) {
        int n = nt * 16 + m;
        float bv = b0[n];
        unsigned u0 = packbf(acc[nt][0] + bv, acc[nt][1] + bv);
        unsigned u1 = packbf(acc[nt][2] + bv, acc[nt][3] + bv);
        y0w[((size_t)(blk * 4 + wv) * 8 + nt) * 64 + lane] = make_uint2(u0, u1);
        float v0 = bflo(u0), v1 = bfhi(u0), v2 = bflo(u1), v3 = bfhi(u1);
        float s  = v0 + v1 + v2 + v3;
        float q2 = v0 * v0 + v1 * v1 + v2 * v2 + v3 * v3;
        s += __shfl_xor(s, 16, 64); q2 += __shfl_xor(q2, 16, 64);
        s += __shfl_xor(s, 32, 64); q2 += __shfl_xor(q2, 32, 64);
        if (q == 0) { wsum[wv][n] = s; wsq[wv][n] = q2; }
    }
    __syncthreads();

    float* slot = slots0 + (size_t)(blk & (NSLOT - 1)) * 256;
    if (t < CM_)
        atomicAdd(&slot[t], wsum[0][t] + wsum[1][t] + wsum[2][t] + wsum[3][t]);
    else
        atomicAdd(&slot[t], wsq[0][t - CM_] + wsq[1][t - CM_] + wsq[2][t - CM_] + wsq[3][t - CM_]);
}

// ---------------------------------------------------------------------------
// K2: load y0 frags (coalesced), BN0+ReLU (scale/shift precomputed in bnp0),
// D->A transform via LDS; MFMA matmul1 with w1F; y1 frag-packed bf16 + BN1
// stats.
// ---------------------------------------------------------------------------
__global__ __launch_bounds__(256) void fused2_kernel(
    const uint2* __restrict__ y0w, const float* __restrict__ bnp0,
    const unsigned short* __restrict__ w1F, const float* __restrict__ b1,
    uint2* __restrict__ y1w, float* __restrict__ slots1)
{
    __shared__ unsigned short x1s[64][CM_ + 8];   // pitch 136 shorts
    __shared__ float wsum[4][CM_], wsq[4][CM_];

    const int t = threadIdx.x;
    const int blk = blockIdx.x;
    const int wv = t >> 6, lane = t & 63;
    const int m = lane & 15, q = lane >> 4;

    // y0 frags -> BN0+ReLU -> bf16 A-tile in LDS
    #pragma unroll
    for (int nt = 0; nt < 8; nt++) {
        int n = nt * 16 + m;
        float sc = bnp0[n], sh = bnp0[CM_ + n];
        uint2 u = y0w[((size_t)(blk * 4 + wv) * 8 + nt) * 64 + lane];
        float v0 = fmaxf(bflo(u.x) * sc + sh, 0.f);
        float v1 = fmaxf(bfhi(u.x) * sc + sh, 0.f);
        float v2 = fmaxf(bflo(u.y) * sc + sh, 0.f);
        float v3 = fmaxf(bfhi(u.y) * sc + sh, 0.f);
        int rb = wv * 16 + q * 4;
        x1s[rb + 0][n] = f2bf(v0);
        x1s[rb + 1][n] = f2bf(v1);
        x1s[rb + 2][n] = f2bf(v2);
        x1s[rb + 3][n] = f2bf(v3);
    }
    __syncthreads();

    const unsigned short* arow = &x1s[wv * 16 + m][q * 8];
    floatx4 acc[8];
    #pragma unroll
    for (int nt = 0; nt < 8; nt++) acc[nt] = (floatx4){0.f, 0.f, 0.f, 0.f};

    #pragma unroll
    for (int kk = 0; kk < 4; kk++) {
        short8 a = *(const short8*)(arow + kk * 32);
        #pragma unroll
        for (int nt = 0; nt < 8; nt++) {
            short8 bw = *(const short8*)(w1F + ((size_t)(kk * 8 + nt) * 64 + lane) * 8);
            acc[nt] = __builtin_amdgcn_mfma_f32_16x16x32_bf16(a, bw, acc[nt], 0, 0, 0);
        }
    }

    #pragma unroll
    for (int nt = 0; nt < 8; nt++) {
        int n = nt * 16 + m;
        float bv = b1[n];
        unsigned u0 = packbf(acc[nt][0] + bv, acc[nt][1] + bv);
        unsigned u1 = packbf(acc[nt][2] + bv, acc[nt][3] + bv);
        y1w[((size_t)(blk * 4 + wv) * 8 + nt) * 64 + lane] = make_uint2(u0, u1);
        float v0 = bflo(u0), v1 = bfhi(u0), v2 = bflo(u1), v3 = bfhi(u1);
        float s  = v0 + v1 + v2 + v3;
        float q2 = v0 * v0 + v1 * v1 + v2 * v2 + v3 * v3;
        s += __shfl_xor(s, 16, 64); q2 += __shfl_xor(q2, 16, 64);
        s += __shfl_xor(s, 32, 64); q2 += __shfl_xor(q2, 32, 64);
        if (q == 0) { wsum[wv][n] = s; wsq[wv][n] = q2; }
    }
    __syncthreads();

    float* slot = slots1 + (size_t)(blk & (NSLOT - 1)) * 256;
    if (t < CM_)
        atomicAdd(&slot[t], wsum[0][t] + wsum[1][t] + wsum[2][t] + wsum[3][t]);
    else
        atomicAdd(&slot[t], wsq[0][t - CM_] + wsq[1][t - CM_] + wsq[2][t - CM_] + wsq[3][t - CM_]);
}

// ---------------------------------------------------------------------------
// K3: BN1+ReLU on y1 frags -> LDS transpose (pitch 140: 16B-aligned,
// 2-way-bank-free column writes) -> fully coalesced f32 row-major stores.
// ---------------------------------------------------------------------------
__global__ __launch_bounds__(256) void bn_out_kernel(
    const uint2* __restrict__ y1w, const float* __restrict__ bnp1,
    float* __restrict__ out)
{
    __shared__ float xo[64][CM_ + 12];    // pitch 140 floats
    const int t = threadIdx.x;
    const int blk = blockIdx.x;
    const int wv = t >> 6, lane = t & 63;
    const int m = lane & 15, q = lane >> 4;

    #pragma unroll
    for (int nt = 0; nt < 8; nt++) {
        int n = nt * 16 + m;
        float sc = bnp1[n], sh = bnp1[CM_ + n];
        uint2 u = y1w[((size_t)(blk * 4 + wv) * 8 + nt) * 64 + lane];
        int rb = wv * 16 + q * 4;
        xo[rb + 0][n] = fmaxf(bflo(u.x) * sc + sh, 0.f);
        xo[rb + 1][n] = fmaxf(bfhi(u.x) * sc + sh, 0.f);
        xo[rb + 2][n] = fmaxf(bflo(u.y) * sc + sh, 0.f);
        xo[rb + 3][n] = fmaxf(bfhi(u.y) * sc + sh, 0.f);
    }
    __syncthreads();

    const int pbase = blk * 64;
    #pragma unroll
    for (int i = 0; i < 8; i++) {
        int idx = t + i * 256;
        int p = idx >> 5, c4 = (idx & 31) << 2;
        float4 v = *(const float4*)&xo[p][c4];
        *(float4*)(out + (size_t)(pbase + p) * CM_ + c4) = v;
    }
}

// ---------------------------------------------------------------------------
extern "C" void kernel_launch(void* const* d_in, const int* in_sizes, int n_in,
                              void* d_out, int out_size, void* d_ws, size_t ws_size,
                              hipStream_t stream)
{
    const float* xyz1  = (const float*)d_in[0];
    const float* xyz2  = (const float*)d_in[1];
    const float* feat1 = (const float*)d_in[2];
    const float* feat2 = (const float*)d_in[3];
    const float* w0    = (const float*)d_in[4];
    const float* b0    = (const float*)d_in[5];
    const float* g0    = (const float*)d_in[6];
    const float* be0   = (const float*)d_in[7];
    const float* w1    = (const float*)d_in[8];
    const float* b1    = (const float*)d_in[9];
    const float* g1    = (const float*)d_in[10];
    const float* be1   = (const float*)d_in[11];
    float* out = (float*)d_out;

    char* ws = (char*)d_ws;
    // ws: slots0 32K | slots1 32K | bnp0 1K | bnp1 1K | sel 1.5M | wgt 1.5M
    //     | w0F 48K | w1F 32K | y0w 33.5M | y1w 33.5M
    float* slots0       = (float*)(ws);
    float* slots1       = (float*)(ws + (size_t)NSLOT * 256 * 4);
    float* bnp0         = (float*)(ws + 2 * (size_t)NSLOT * 256 * 4);
    float* bnp1         = bnp0 + 256;
    char*  p            = (char*)(bnp1 + 256);
    int*   sel          = (int*)p;             p += (size_t)NTOT * NS_ * 4;
    float* wgt          = (float*)p;           p += (size_t)NTOT * NS_ * 4;
    unsigned short* w0F = (unsigned short*)p;  p += (size_t)CIN_ * CM_ * 2;
    unsigned short* w1F = (unsigned short*)p;  p += (size_t)CM_ * CM_ * 2;
    uint2* y0w          = (uint2*)p;           p += (size_t)NTOT * CM_ * 2;
    uint2* y1w          = (uint2*)p;

    hipMemsetAsync(ws, 0, 2 * (size_t)NSLOT * 256 * 4, stream);  // zero stat slots

    prep_knn_kernel<<<20 + NTOT / 256, 256, 0, stream>>>(w0, w1, xyz1, xyz2,
                                                         w0F, w1F, sel, wgt);
    fused1_kernel<<<NTOT / 64, 256, 0, stream>>>(feat1, feat2, sel, wgt,
                                                 w0F, b0, y0w, slots0);
    bnfin_kernel<<<1, 128, 0, stream>>>(slots0, g0, be0, bnp0);
    fused2_kernel<<<NTOT / 64, 256, 0, stream>>>(y0w, bnp0, w1F, b1, y1w, slots1);
    bnfin_kernel<<<1, 128, 0, stream>>>(slots1, g1, be1, bnp1);
    bn_out_kernel<<<NTOT / 64, 256, 0, stream>>>(y1w, bnp1, out);
}

// Round 8
// 221.555 us; speedup vs baseline: 1.0867x; 1.0382x over previous
//
#include <hip/hip_runtime.h>

// Problem constants (match reference)
#define H_    64
#define W_    1024
#define NPT   65536            // H*W
#define NTOT  131072           // B*NPT
#define C1_   64
#define C2_   128
#define CIN_  192
#define CM_   128
#define NS_   3
#define DIST2_ 10000.0f
#define BN_EPS_ 1e-5f
#define NSLOT 32               // BN-stat accumulator slots

typedef __attribute__((ext_vector_type(8))) short short8;   // 8 bf16
typedef __attribute__((ext_vector_type(4))) float floatx4;  // MFMA C/D

static __device__ __forceinline__ unsigned short f2bf(float f) {
    unsigned int u = __float_as_uint(f);
    u += 0x7fffu + ((u >> 16) & 1u);      // round-nearest-even
    return (unsigned short)(u >> 16);
}
static __device__ __forceinline__ float bflo(unsigned u) { return __uint_as_float(u << 16); }
static __device__ __forceinline__ float bfhi(unsigned u) { return __uint_as_float(u & 0xffff0000u); }
static __device__ __forceinline__ unsigned packbf(float a, float b) {
    return (unsigned)f2bf(a) | ((unsigned)f2bf(b) << 16);
}

// ---------------------------------------------------------------------------
// K0: blocks 0..19 build fragment-major bf16 weights
// (w0F[((kk*8+nt)*64+lane)*8+j] -> coalesced 1KB B-frag wave loads);
// blocks 20.. do structured-grid KNN (reference 5x5 row-major scan order).
// ---------------------------------------------------------------------------
__global__ __launch_bounds__(256) void prep_knn_kernel(
    const float* __restrict__ w0, const float* __restrict__ w1,
    const float* __restrict__ xyz1, const float* __restrict__ xyz2,
    unsigned short* __restrict__ w0F, unsigned short* __restrict__ w1F,
    int* __restrict__ sel, float* __restrict__ wgt)
{
    const int blk = blockIdx.x;
    if (blk < 20) {
        int tid = blk * 256 + threadIdx.x;
        if (tid < 3072) {                       // w0F: 6kk x 8nt x 64lane chunks
            int c = tid, lane = c & 63, nt = (c >> 6) & 7, kk = c >> 9;
            int n = nt * 16 + (lane & 15);
            int kb = kk * 32 + (lane >> 4) * 8;
            #pragma unroll
            for (int j = 0; j < 8; j++)
                w0F[(size_t)c * 8 + j] = f2bf(w0[(size_t)(kb + j) * CM_ + n]);
        } else if (tid < 5120) {                // w1F: 4kk x 8nt x 64lane
            int c = tid - 3072, lane = c & 63, nt = (c >> 6) & 7, kk = c >> 9;
            int n = nt * 16 + (lane & 15);
            int kb = kk * 32 + (lane >> 4) * 8;
            #pragma unroll
            for (int j = 0; j < 8; j++)
                w1F[(size_t)c * 8 + j] = f2bf(w1[(size_t)(kb + j) * CM_ + n]);
        }
        return;
    }

    int pt = (blk - 20) * 256 + threadIdx.x;
    if (pt >= NTOT) return;
    int bidx = pt / NPT, n = pt % NPT;
    int h = n / W_, w = n % W_;

    const float* p1 = xyz1 + (size_t)pt * 3;
    float x1 = p1[0], y1 = p1[1], z1 = p1[2];
    const float* x2b = xyz2 + (size_t)bidx * NPT * 3;

    int   s0 = 0, s1 = 0, s2 = 0;
    float d0 = 0.f, d1 = 0.f, d2 = 0.f;
    int cnt = 0;
    for (int dh = -2; dh <= 2; dh++) {
        int nh = h + dh;
        bool okh = (nh >= 0) && (nh < H_);
        for (int dw = -2; dw <= 2; dw++) {
            int nw = w + dw;
            if (!(okh && nw >= 0 && nw < W_)) continue;
            int nidx = nh * W_ + nw;
            const float* p2 = x2b + (size_t)nidx * 3;
            float dx = p2[0] - x1, dy = p2[1] - y1, dz = p2[2] - z1;
            float sq = dx * dx + dy * dy + dz * dz;
            if (sq < DIST2_ && cnt < NS_) {
                if (cnt == 0)      { s0 = nidx; d0 = sq; }
                else if (cnt == 1) { s1 = nidx; d1 = sq; }
                else               { s2 = nidx; d2 = sq; }
                cnt++;
            }
        }
    }
    float self2 = x1 * x1 + y1 * y1 + z1 * z1;
    float dd0 = (cnt > 0) ? d0 : self2;
    float dd1 = (cnt > 1) ? d1 : self2;
    float dd2 = (cnt > 2) ? d2 : self2;
    dd0 = fmaxf(dd0, 1e-10f); dd1 = fmaxf(dd1, 1e-10f); dd2 = fmaxf(dd2, 1e-10f);
    float i0 = 1.0f / dd0, i1 = 1.0f / dd1, i2 = 1.0f / dd2;
    float norm = i0 + i1 + i2;
    sel[(size_t)pt * NS_ + 0] = (cnt > 0) ? s0 : 0;
    sel[(size_t)pt * NS_ + 1] = (cnt > 1) ? s1 : 0;
    sel[(size_t)pt * NS_ + 2] = (cnt > 2) ? s2 : 0;
    wgt[(size_t)pt * NS_ + 0] = (cnt > 0) ? i0 / norm : 0.f;
    wgt[(size_t)pt * NS_ + 1] = (cnt > 1) ? i1 / norm : 0.f;
    wgt[(size_t)pt * NS_ + 2] = (cnt > 2) ? i2 / norm : 0.f;
}

// ---------------------------------------------------------------------------
// bnfin: 1-block kernel. Reduce NSLOT slot-accumulators -> per-channel BN
// scale/shift into bnp[0:128]=scale, bnp[128:256]=shift.
// ---------------------------------------------------------------------------
__global__ __launch_bounds__(128) void bnfin_kernel(
    const float* __restrict__ slots, const float* __restrict__ g,
    const float* __restrict__ be, float* __restrict__ bnp)
{
    int t = threadIdx.x;                // 128 threads, one channel each
    float s = 0.f, q2 = 0.f;
    #pragma unroll
    for (int sl = 0; sl < NSLOT; sl++) {
        s  += slots[sl * 256 + t];
        q2 += slots[sl * 256 + CM_ + t];
    }
    const float invn = 1.0f / (float)NTOT;
    float mu = s * invn, var = q2 * invn - mu * mu;
    float sc = g[t] * rsqrtf(var + BN_EPS_);
    bnp[t] = sc;
    bnp[CM_ + t] = be[t] - mu * sc;
}

// ---------------------------------------------------------------------------
// K1: 128 points/block (2 M-tiles). Gather staged via LDS (coalesced
// channel-major); feat1 direct to A-frags. MFMA loop: per kk, prefetch all
// 8 B-frags into regs (parallel loads), then 2 MFMAs per B-frag (tile0+tile1)
// -> half the latency exposure per FLOP. y0 frag-packed bf16; BN0 stats.
// ---------------------------------------------------------------------------
__global__ __launch_bounds__(256, 3) void fused1_kernel(
    const float* __restrict__ feat1, const float* __restrict__ feat2,
    const int* __restrict__ sel, const float* __restrict__ wgt,
    const unsigned short* __restrict__ w0F, const float* __restrict__ b0,
    uint2* __restrict__ y0w, float* __restrict__ slots0)
{
    __shared__ unsigned short xstage[128][CM_ + 8];  // interp channels, pitch 136
    __shared__ int   selL[128][NS_];
    __shared__ float wgtL[128][NS_];
    __shared__ float wsum[4][CM_], wsq[4][CM_];

    const int t = threadIdx.x;
    const int blk = blockIdx.x;                 // 1024 blocks
    const int pbase = blk * 128;
    const int bidx = blk >> 9;                  // 512 blocks per batch
    const int wv = t >> 6, lane = t & 63;
    const int m = lane & 15, q = lane >> 4;
    const int row0 = pbase + wv * 16 + m;       // tile0 row
    const int row1 = row0 + 64;                 // tile1 row

    #pragma unroll
    for (int i = 0; i < 2; i++) {
        int idx = t + i * 256;
        if (idx < 128 * NS_) {
            ((int*)selL)[idx]   = sel[(size_t)pbase * NS_ + idx];
            ((float*)wgtL)[idx] = wgt[(size_t)pbase * NS_ + idx];
        }
    }

    // feat1 -> A-frags kk=0,1 for both tiles, directly from global
    short8 af0[2], af1[2];
    #pragma unroll
    for (int kk = 0; kk < 2; kk++) {
        const float* s0p = feat1 + (size_t)row0 * C1_ + kk * 32 + q * 8;
        const float* s1p = feat1 + (size_t)row1 * C1_ + kk * 32 + q * 8;
        float4 fa = *(const float4*)(s0p), fb = *(const float4*)(s0p + 4);
        float4 ga = *(const float4*)(s1p), gb = *(const float4*)(s1p + 4);
        short8 a, b;
        a[0] = f2bf(fa.x); a[1] = f2bf(fa.y); a[2] = f2bf(fa.z); a[3] = f2bf(fa.w);
        a[4] = f2bf(fb.x); a[5] = f2bf(fb.y); a[6] = f2bf(fb.z); a[7] = f2bf(fb.w);
        b[0] = f2bf(ga.x); b[1] = f2bf(ga.y); b[2] = f2bf(ga.z); b[3] = f2bf(ga.w);
        b[4] = f2bf(gb.x); b[5] = f2bf(gb.y); b[6] = f2bf(gb.z); b[7] = f2bf(gb.w);
        af0[kk] = a; af1[kk] = b;
    }
    __syncthreads();

    // IDW interp -> xstage (coalesced: 32 lanes span one row's 128 channels)
    const float* f2b = feat2 + (size_t)bidx * NPT * C2_;
    #pragma unroll
    for (int i = 0; i < 16; i++) {
        int idx = t + i * 256;
        int p = idx >> 5, c4 = (idx & 31) << 2;
        float ax = 0.f, ay = 0.f, az = 0.f, aw = 0.f;
        #pragma unroll
        for (int j = 0; j < NS_; j++) {
            float wj = wgtL[p][j];
            const float4 f = *(const float4*)(f2b + (size_t)selL[p][j] * C2_ + c4);
            ax += wj * f.x; ay += wj * f.y; az += wj * f.z; aw += wj * f.w;
        }
        ushort4 u;
        u.x = f2bf(ax); u.y = f2bf(ay); u.z = f2bf(az); u.w = f2bf(aw);
        *(ushort4*)&xstage[p][c4] = u;
    }
    __syncthreads();

    floatx4 acc0[8], acc1[8];
    #pragma unroll
    for (int nt = 0; nt < 8; nt++) {
        acc0[nt] = (floatx4){0.f, 0.f, 0.f, 0.f};
        acc1[nt] = (floatx4){0.f, 0.f, 0.f, 0.f};
    }

    const int lr0 = wv * 16 + m, lr1 = lr0 + 64;
    #pragma unroll
    for (int kk = 0; kk < 6; kk++) {
        short8 bw[8];                           // prefetch all 8 B-frags
        #pragma unroll
        for (int nt = 0; nt < 8; nt++)
            bw[nt] = *(const short8*)(w0F + ((size_t)(kk * 8 + nt) * 64 + lane) * 8);
        short8 a0, a1;
        if (kk < 2) { a0 = af0[kk]; a1 = af1[kk]; }
        else {
            a0 = *(const short8*)&xstage[lr0][(kk - 2) * 32 + q * 8];
            a1 = *(const short8*)&xstage[lr1][(kk - 2) * 32 + q * 8];
        }
        #pragma unroll
        for (int nt = 0; nt < 8; nt++) {
            acc0[nt] = __builtin_amdgcn_mfma_f32_16x16x32_bf16(a0, bw[nt], acc0[nt], 0, 0, 0);
            acc1[nt] = __builtin_amdgcn_mfma_f32_16x16x32_bf16(a1, bw[nt], acc1[nt], 0, 0, 0);
        }
    }

    // epilogue: both tiles; stats accumulated across tiles, one shfl pass
    #pragma unroll
    for (int nt = 0; nt < 8; nt++) {
        int n = nt * 16 + m;
        float bv = b0[n];
        unsigned u0 = packbf(acc0[nt][0] + bv, acc0[nt][1] + bv);
        unsigned u1 = packbf(acc0[nt][2] + bv, acc0[nt][3] + bv);
        unsigned u2 = packbf(acc1[nt][0] + bv, acc1[nt][1] + bv);
        unsigned u3 = packbf(acc1[nt][2] + bv, acc1[nt][3] + bv);
        int g0i = blk * 2;                      // tile64 ids: blk*2, blk*2+1
        y0w[((size_t)(g0i * 4 + wv) * 8 + nt) * 64 + lane]       = make_uint2(u0, u1);
        y0w[((size_t)((g0i + 1) * 4 + wv) * 8 + nt) * 64 + lane] = make_uint2(u2, u3);
        float v0 = bflo(u0), v1 = bfhi(u0), v2 = bflo(u1), v3 = bfhi(u1);
        float v4 = bflo(u2), v5 = bfhi(u2), v6 = bflo(u3), v7 = bfhi(u3);
        float s  = v0 + v1 + v2 + v3 + v4 + v5 + v6 + v7;
        float q2 = v0*v0 + v1*v1 + v2*v2 + v3*v3 + v4*v4 + v5*v5 + v6*v6 + v7*v7;
        s += __shfl_xor(s, 16, 64); q2 += __shfl_xor(q2, 16, 64);
        s += __shfl_xor(s, 32, 64); q2 += __shfl_xor(q2, 32, 64);
        if (q == 0) { wsum[wv][n] = s; wsq[wv][n] = q2; }
    }
    __syncthreads();

    float* slot = slots0 + (size_t)(blk & (NSLOT - 1)) * 256;
    if (t < CM_)
        atomicAdd(&slot[t], wsum[0][t] + wsum[1][t] + wsum[2][t] + wsum[3][t]);
    else
        atomicAdd(&slot[t], wsq[0][t - CM_] + wsq[1][t - CM_] + wsq[2][t - CM_] + wsq[3][t - CM_]);
}

// ---------------------------------------------------------------------------
// K2: 128 points/block, same 2-tile B-frag reuse. y0 frags (coalesced) ->
// BN0+ReLU -> LDS A-tiles; MFMA matmul1; y1 frag-packed bf16 + BN1 stats.
// ---------------------------------------------------------------------------
__global__ __launch_bounds__(256, 3) void fused2_kernel(
    const uint2* __restrict__ y0w, const float* __restrict__ bnp0,
    const unsigned short* __restrict__ w1F, const float* __restrict__ b1,
    uint2* __restrict__ y1w, float* __restrict__ slots1)
{
    __shared__ unsigned short x1s[128][CM_ + 8];   // pitch 136 shorts
    __shared__ float wsum[4][CM_], wsq[4][CM_];

    const int t = threadIdx.x;
    const int blk = blockIdx.x;                 // 1024 blocks
    const int wv = t >> 6, lane = t & 63;
    const int m = lane & 15, q = lane >> 4;
    const int g0i = blk * 2;

    // y0 frags (both tiles) -> BN0+ReLU -> bf16 A-tiles in LDS
    #pragma unroll
    for (int nt = 0; nt < 8; nt++) {
        int n = nt * 16 + m;
        float sc = bnp0[n], sh = bnp0[CM_ + n];
        uint2 ua = y0w[((size_t)(g0i * 4 + wv) * 8 + nt) * 64 + lane];
        uint2 ub = y0w[((size_t)((g0i + 1) * 4 + wv) * 8 + nt) * 64 + lane];
        int rb = wv * 16 + q * 4;
        x1s[rb + 0][n] = f2bf(fmaxf(bflo(ua.x) * sc + sh, 0.f));
        x1s[rb + 1][n] = f2bf(fmaxf(bfhi(ua.x) * sc + sh, 0.f));
        x1s[rb + 2][n] = f2bf(fmaxf(bflo(ua.y) * sc + sh, 0.f));
        x1s[rb + 3][n] = f2bf(fmaxf(bfhi(ua.y) * sc + sh, 0.f));
        x1s[64 + rb + 0][n] = f2bf(fmaxf(bflo(ub.x) * sc + sh, 0.f));
        x1s[64 + rb + 1][n] = f2bf(fmaxf(bfhi(ub.x) * sc + sh, 0.f));
        x1s[64 + rb + 2][n] = f2bf(fmaxf(bflo(ub.y) * sc + sh, 0.f));
        x1s[64 + rb + 3][n] = f2bf(fmaxf(bfhi(ub.y) * sc + sh, 0.f));
    }
    __syncthreads();

    const int lr0 = wv * 16 + m, lr1 = lr0 + 64;
    floatx4 acc0[8], acc1[8];
    #pragma unroll
    for (int nt = 0; nt < 8; nt++) {
        acc0[nt] = (floatx4){0.f, 0.f, 0.f, 0.f};
        acc1[nt] = (floatx4){0.f, 0.f, 0.f, 0.f};
    }

    #pragma unroll
    for (int kk = 0; kk < 4; kk++) {
        short8 bw[8];
        #pragma unroll
        for (int nt = 0; nt < 8; nt++)
            bw[nt] = *(const short8*)(w1F + ((size_t)(kk * 8 + nt) * 64 + lane) * 8);
        short8 a0 = *(const short8*)&x1s[lr0][kk * 32 + q * 8];
        short8 a1 = *(const short8*)&x1s[lr1][kk * 32 + q * 8];
        #pragma unroll
        for (int nt = 0; nt < 8; nt++) {
            acc0[nt] = __builtin_amdgcn_mfma_f32_16x16x32_bf16(a0, bw[nt], acc0[nt], 0, 0, 0);
            acc1[nt] = __builtin_amdgcn_mfma_f32_16x16x32_bf16(a1, bw[nt], acc1[nt], 0, 0, 0);
        }
    }

    #pragma unroll
    for (int nt = 0; nt < 8; nt++) {
        int n = nt * 16 + m;
        float bv = b1[n];
        unsigned u0 = packbf(acc0[nt][0] + bv, acc0[nt][1] + bv);
        unsigned u1 = packbf(acc0[nt][2] + bv, acc0[nt][3] + bv);
        unsigned u2 = packbf(acc1[nt][0] + bv, acc1[nt][1] + bv);
        unsigned u3 = packbf(acc1[nt][2] + bv, acc1[nt][3] + bv);
        y1w[((size_t)(g0i * 4 + wv) * 8 + nt) * 64 + lane]       = make_uint2(u0, u1);
        y1w[((size_t)((g0i + 1) * 4 + wv) * 8 + nt) * 64 + lane] = make_uint2(u2, u3);
        float v0 = bflo(u0), v1 = bfhi(u0), v2 = bflo(u1), v3 = bfhi(u1);
        float v4 = bflo(u2), v5 = bfhi(u2), v6 = bflo(u3), v7 = bfhi(u3);
        float s  = v0 + v1 + v2 + v3 + v4 + v5 + v6 + v7;
        float q2 = v0*v0 + v1*v1 + v2*v2 + v3*v3 + v4*v4 + v5*v5 + v6*v6 + v7*v7;
        s += __shfl_xor(s, 16, 64); q2 += __shfl_xor(q2, 16, 64);
        s += __shfl_xor(s, 32, 64); q2 += __shfl_xor(q2, 32, 64);
        if (q == 0) { wsum[wv][n] = s; wsq[wv][n] = q2; }
    }
    __syncthreads();

    float* slot = slots1 + (size_t)(blk & (NSLOT - 1)) * 256;
    if (t < CM_)
        atomicAdd(&slot[t], wsum[0][t] + wsum[1][t] + wsum[2][t] + wsum[3][t]);
    else
        atomicAdd(&slot[t], wsq[0][t - CM_] + wsq[1][t - CM_] + wsq[2][t - CM_] + wsq[3][t - CM_]);
}

// ---------------------------------------------------------------------------
// K3: BN1+ReLU on y1 frags -> LDS transpose -> coalesced f32 row-major out.
// ---------------------------------------------------------------------------
__global__ __launch_bounds__(256) void bn_out_kernel(
    const uint2* __restrict__ y1w, const float* __restrict__ bnp1,
    float* __restrict__ out)
{
    __shared__ float xo[64][CM_ + 12];    // pitch 140 floats
    const int t = threadIdx.x;
    const int blk = blockIdx.x;           // 2048 blocks, one 64-pt tile each
    const int wv = t >> 6, lane = t & 63;
    const int m = lane & 15, q = lane >> 4;

    #pragma unroll
    for (int nt = 0; nt < 8; nt++) {
        int n = nt * 16 + m;
        float sc = bnp1[n], sh = bnp1[CM_ + n];
        uint2 u = y1w[((size_t)(blk * 4 + wv) * 8 + nt) * 64 + lane];
        int rb = wv * 16 + q * 4;
        xo[rb + 0][n] = fmaxf(bflo(u.x) * sc + sh, 0.f);
        xo[rb + 1][n] = fmaxf(bfhi(u.x) * sc + sh, 0.f);
        xo[rb + 2][n] = fmaxf(bflo(u.y) * sc + sh, 0.f);
        xo[rb + 3][n] = fmaxf(bfhi(u.y) * sc + sh, 0.f);
    }
    __syncthreads();

    const int pbase = blk * 64;
    #pragma unroll
    for (int i = 0; i < 8; i++) {
        int idx = t + i * 256;
        int p = idx >> 5, c4 = (idx & 31) << 2;
        float4 v = *(const float4*)&xo[p][c4];
        *(float4*)(out + (size_t)(pbase + p) * CM_ + c4) = v;
    }
}

// ---------------------------------------------------------------------------
extern "C" void kernel_launch(void* const* d_in, const int* in_sizes, int n_in,
                              void* d_out, int out_size, void* d_ws, size_t ws_size,
                              hipStream_t stream)
{
    const float* xyz1  = (const float*)d_in[0];
    const float* xyz2  = (const float*)d_in[1];
    const float* feat1 = (const float*)d_in[2];
    const float* feat2 = (const float*)d_in[3];
    const float* w0    = (const float*)d_in[4];
    const float* b0    = (const float*)d_in[5];
    const float* g0    = (const float*)d_in[6];
    const float* be0   = (const float*)d_in[7];
    const float* w1    = (const float*)d_in[8];
    const float* b1    = (const float*)d_in[9];
    const float* g1    = (const float*)d_in[10];
    const float* be1   = (const float*)d_in[11];
    float* out = (float*)d_out;

    char* ws = (char*)d_ws;
    // ws: slots0 32K | slots1 32K | bnp0 1K | bnp1 1K | sel 1.5M | wgt 1.5M
    //     | w0F 48K | w1F 32K | y0w 33.5M | y1w 33.5M
    float* slots0       = (float*)(ws);
    float* slots1       = (float*)(ws + (size_t)NSLOT * 256 * 4);
    float* bnp0         = (float*)(ws + 2 * (size_t)NSLOT * 256 * 4);
    float* bnp1         = bnp0 + 256;
    char*  p            = (char*)(bnp1 + 256);
    int*   sel          = (int*)p;             p += (size_t)NTOT * NS_ * 4;
    float* wgt          = (float*)p;           p += (size_t)NTOT * NS_ * 4;
    unsigned short* w0F = (unsigned short*)p;  p += (size_t)CIN_ * CM_ * 2;
    unsigned short* w1F = (unsigned short*)p;  p += (size_t)CM_ * CM_ * 2;
    uint2* y0w          = (uint2*)p;           p += (size_t)NTOT * CM_ * 2;
    uint2* y1w          = (uint2*)p;

    hipMemsetAsync(ws, 0, 2 * (size_t)NSLOT * 256 * 4, stream);  // zero stat slots

    prep_knn_kernel<<<20 + NTOT / 256, 256, 0, stream>>>(w0, w1, xyz1, xyz2,
                                                         w0F, w1F, sel, wgt);
    fused1_kernel<<<NTOT / 128, 256, 0, stream>>>(feat1, feat2, sel, wgt,
                                                  w0F, b0, y0w, slots0);
    bnfin_kernel<<<1, 128, 0, stream>>>(slots0, g0, be0, bnp0);
    fused2_kernel<<<NTOT / 128, 256, 0, stream>>>(y0w, bnp0, w1F, b1, y1w, slots1);
    bnfin_kernel<<<1, 128, 0, stream>>>(slots1, g1, be1, bnp1);
    bn_out_kernel<<<NTOT / 64, 256, 0, stream>>>(y1w, bnp1, out);
}